// Round 14
// baseline (173.359 us; speedup 1.0000x reference)
//
#include <hip/hip_runtime.h>
#include <stdint.h>

typedef __attribute__((ext_vector_type(8))) short s16x8;
typedef __attribute__((ext_vector_type(4))) float f32x4;

#define MFMA16(a, b, c) __builtin_amdgcn_mfma_f32_16x16x32_bf16((a), (b), (c), 0, 0, 0)

// ---------- helpers ----------
__device__ __forceinline__ unsigned short f2bf(float f) {
    unsigned int u = __float_as_uint(f);
    return (unsigned short)((u + 0x7FFFu + ((u >> 16) & 1u)) >> 16);
}
__device__ __forceinline__ float bf2f(unsigned short h) {
    return __uint_as_float(((unsigned int)h) << 16);
}
__device__ __forceinline__ void cvt8(unsigned short* dst, const float* src) {
    const float4 f0 = *(const float4*)(src);
    const float4 f1 = *(const float4*)(src + 4);
    s16x8 v;
    v[0] = (short)f2bf(f0.x); v[1] = (short)f2bf(f0.y);
    v[2] = (short)f2bf(f0.z); v[3] = (short)f2bf(f0.w);
    v[4] = (short)f2bf(f1.x); v[5] = (short)f2bf(f1.y);
    v[6] = (short)f2bf(f1.z); v[7] = (short)f2bf(f1.w);
    *(s16x8*)dst = v;
}
// async global->LDS DMA, 16 B/lane; LDS base wave-uniform, lane i -> base+i*16.
__device__ __forceinline__ void gl_lds16(const unsigned short* g, unsigned short* l) {
    __builtin_amdgcn_global_load_lds(
        (const __attribute__((address_space(1))) unsigned int*)g,
        (__attribute__((address_space(3))) unsigned int*)l,
        16, 0, 0);
}

// ---------- merged fp32 -> bf16 convert for x / Wqkv / Wfc (one launch) ----------
__global__ __launch_bounds__(256) void cvt_all(const float* __restrict__ x,
                                               const float* __restrict__ wq,
                                               const float* __restrict__ wf,
                                               unsigned short* __restrict__ xb,
                                               unsigned short* __restrict__ wqb,
                                               unsigned short* __restrict__ wfb) {
    const int blk = blockIdx.x;  // 0..3135
    const float* src;
    unsigned short* dst;
    int base;
    if (blk < 2048)      { src = x;  dst = xb;  base = blk; }
    else if (blk < 2624) { src = wq; dst = wqb; base = blk - 2048; }
    else                 { src = wf; dst = wfb; base = blk - 2624; }
    const int i = (base * 256 + threadIdx.x) * 8;
    cvt8(&dst[i], &src[i]);
}

// ---------- GEMM 128(M)x64(N), double-buffered DMA staging (r13) ----------
template <bool OUT_F32>
__global__ __launch_bounds__(256) void gemm_mn(const unsigned short* __restrict__ A,
                                               const unsigned short* __restrict__ Bw,
                                               void* __restrict__ Cout, int K, int N) {
    const int bm = blockIdx.x, bn = blockIdx.y;
    const int t = threadIdx.x;
    const int lane = t & 63, w = t >> 6;
    const int quad = lane >> 4, col = lane & 15;
    const int wm = (w >> 1) * 64, wn = (w & 1) * 32;

    __shared__ alignas(16) unsigned short As[2][128 * 64];  // 2 x 16 KB, unpadded
    __shared__ alignas(16) unsigned short Bs[2][64 * 64];   // 2 x  8 KB, unpadded

    f32x4 acc[4][2];
#pragma unroll
    for (int i = 0; i < 4; ++i)
#pragma unroll
        for (int j = 0; j < 2; ++j) acc[i][j] = (f32x4){0.f, 0.f, 0.f, 0.f};

    const int lrow = lane >> 3;       // 0..7
    const int lcol = (lane & 7) * 8;  // 0..56 shorts
    const unsigned short* Ap = A + (size_t)(bm * 128 + w * 8 + lrow) * K + lcol;
    const unsigned short* Bp = Bw + (size_t)(bn * 64 + w * 8 + lrow) * K + lcol;

    // prime tile 0 into buffer 0
#pragma unroll
    for (int j = 0; j < 4; ++j)
        gl_lds16(Ap + (size_t)(j * 32) * K, &As[0][(j * 32 + w * 8) * 64]);
#pragma unroll
    for (int j = 0; j < 2; ++j)
        gl_lds16(Bp + (size_t)(j * 32) * K, &Bs[0][(j * 32 + w * 8) * 64]);
    __syncthreads();  // drain: tile 0 visible

    for (int k0 = 0; k0 < K; k0 += 64) {
        const int p = (k0 >> 6) & 1;
        if (k0 + 64 < K) {  // stream next tile into the other buffer (no drain)
#pragma unroll
            for (int j = 0; j < 4; ++j)
                gl_lds16(Ap + (size_t)(j * 32) * K + k0 + 64, &As[p ^ 1][(j * 32 + w * 8) * 64]);
#pragma unroll
            for (int j = 0; j < 2; ++j)
                gl_lds16(Bp + (size_t)(j * 32) * K + k0 + 64, &Bs[p ^ 1][(j * 32 + w * 8) * 64]);
        }
#pragma unroll
        for (int s = 0; s < 2; ++s) {
            s16x8 af[4], bfr[2];
#pragma unroll
            for (int i = 0; i < 4; ++i)
                af[i] = *(const s16x8*)&As[p][(wm + i * 16 + col) * 64 + s * 32 + quad * 8];
#pragma unroll
            for (int j = 0; j < 2; ++j)
                bfr[j] = *(const s16x8*)&Bs[p][(wn + j * 16 + col) * 64 + s * 32 + quad * 8];
#pragma unroll
            for (int i = 0; i < 4; ++i)
#pragma unroll
                for (int j = 0; j < 2; ++j)
                    acc[i][j] = MFMA16(af[i], bfr[j], acc[i][j]);
        }
        __syncthreads();
    }
    const int rowb = bm * 128 + wm + quad * 4;
    const int colb = bn * 64 + wn + col;
#pragma unroll
    for (int i = 0; i < 4; ++i)
#pragma unroll
        for (int j = 0; j < 2; ++j)
#pragma unroll
            for (int r = 0; r < 4; ++r) {
                size_t off = (size_t)(rowb + i * 16 + r) * N + colb + j * 16;
                if (OUT_F32) ((float*)Cout)[off] = acc[i][j][r];
                else ((unsigned short*)Cout)[off] = f2bf(acc[i][j][r]);
            }
}

// ---------- LayerNorm over 1152, one WAVE per row (r13) ----------
__global__ __launch_bounds__(64) void ln_row(unsigned short* __restrict__ qkvn,
                                             const float* __restrict__ gamma,
                                             const float* __restrict__ beta,
                                             unsigned short* __restrict__ vT) {
    const int row = blockIdx.x;  // b*2048 + l
    const int b = row >> 11, l = row & 2047;
    unsigned short* rp = qkvn + (size_t)row * 1152;
    const int lane = threadIdx.x;

    s16x8 v0 = *(const s16x8*)&rp[lane * 8];
    s16x8 v1 = *(const s16x8*)&rp[512 + lane * 8];
    unsigned int v2u = *(const unsigned int*)&rp[1024 + lane * 2];

    float f0[8], f1[8], f2[2];
    float s = 0.f, s2 = 0.f;
#pragma unroll
    for (int e = 0; e < 8; ++e) {
        f0[e] = bf2f((unsigned short)v0[e]);
        f1[e] = bf2f((unsigned short)v1[e]);
        s += f0[e] + f1[e];
        s2 += f0[e] * f0[e] + f1[e] * f1[e];
    }
    f2[0] = bf2f((unsigned short)(v2u & 0xFFFF));
    f2[1] = bf2f((unsigned short)(v2u >> 16));
    s += f2[0] + f2[1];
    s2 += f2[0] * f2[0] + f2[1] * f2[1];

#pragma unroll
    for (int off = 1; off < 64; off <<= 1) {
        s += __shfl_xor(s, off);
        s2 += __shfl_xor(s2, off);
    }
    const float mu = s * (1.0f / 1152.0f);
    float var = s2 * (1.0f / 1152.0f) - mu * mu;
    var = fmaxf(var, 0.0f);
    const float rstd = rsqrtf(var + 1e-5f);

    {
        s16x8 o;
#pragma unroll
        for (int e = 0; e < 8; ++e)
            o[e] = (short)f2bf((f0[e] - mu) * rstd * gamma[lane * 8 + e] + beta[lane * 8 + e]);
        *(s16x8*)&rp[lane * 8] = o;
        if (lane >= 8 && lane < 16) {  // v head (cols 64..127) -> transposed copy
            const int d0 = lane * 8 - 64;
#pragma unroll
            for (int e = 0; e < 8; ++e)
                vT[((size_t)(b * 64 + d0 + e)) * 2048 + l] = (unsigned short)o[e];
        }
    }
    {
        s16x8 o;
#pragma unroll
        for (int e = 0; e < 8; ++e)
            o[e] = (short)f2bf((f1[e] - mu) * rstd * gamma[512 + lane * 8 + e] + beta[512 + lane * 8 + e]);
        *(s16x8*)&rp[512 + lane * 8] = o;
    }
    {
        unsigned short o0 = f2bf((f2[0] - mu) * rstd * gamma[1024 + lane * 2] + beta[1024 + lane * 2]);
        unsigned short o1 = f2bf((f2[1] - mu) * rstd * gamma[1025 + lane * 2] + beta[1025 + lane * 2]);
        *(unsigned int*)&rp[1024 + lane * 2] = ((unsigned int)o1 << 16) | o0;
    }
}

// ---------- Flash-style causal multi-query attention, TRANSPOSED score path ----------
// r12 structure, but computes S^T = K*Q^T and O^T = V^T*P^T by MFMA operand
// swap. For mfma_16x16x32, A and B fragments share the lane layout
// [idx=lane&15][k=quad*8+j], so ALL LDS fragment reads are unchanged; only the
// C-fragment meaning flips: lane now holds (k=quad*4+r, q=col) for S and
// (d=quad*4+r, q=col) for O. Payoff: P-write becomes 4x ds_write_b64 (was 16x
// ds_write_b16 scatter) and the epilogue becomes 4x 8B stores (was 16x 2B).
// Math is the same sums in the same order -> bit-identical output expected.
__global__ __launch_bounds__(512) void attn_kernel(const unsigned short* __restrict__ qkvn,
                                                   const unsigned short* __restrict__ vT,
                                                   unsigned short* __restrict__ obuf) {
    const int b = blockIdx.x >> 3, hp = blockIdx.x & 7;
    const int qb = 31 - blockIdx.y;  // longest tiles dispatched first
    const int t = threadIdx.x;
    const int lane = t & 63, w = t >> 6;
    const int quad = lane >> 4, col = lane & 15;
    const int hl = w >> 2, wq = w & 3;   // head-local, wave-in-head

    __shared__ alignas(16) unsigned short Ks[2][64][72];
    __shared__ alignas(16) unsigned short Vts[2][64][72];   // [d][j]
    __shared__ alignas(16) unsigned short PQ[8][16][72];    // Q-stage, then per-wave P^T as [q][k]

    unsigned short(*Qs)[72] = (unsigned short(*)[72])PQ;    // view as [128][72]

    const int rs = t >> 3;        // 0..63
    const int cs = (t & 7) * 8;   // 0..56

    // stage Q for both heads, pre-scaled by 1/8 (exact in bf16)
#pragma unroll
    for (int hh = 0; hh < 2; ++hh) {
        const unsigned short* qsrc =
            qkvn + (size_t)(b * 2048 + qb * 64 + rs) * 1152 + 128 + (hp * 2 + hh) * 64 + cs;
        s16x8 v = *(const s16x8*)qsrc;
#pragma unroll
        for (int e = 0; e < 8; ++e)
            v[e] = (short)f2bf(bf2f((unsigned short)v[e]) * 0.125f);
        *(s16x8*)&Qs[hh * 64 + rs][cs] = v;
    }
    __syncthreads();
    const s16x8 qf0 = *(const s16x8*)&Qs[hl * 64 + wq * 16 + col][quad * 8];
    const s16x8 qf1 = *(const s16x8*)&Qs[hl * 64 + wq * 16 + col][32 + quad * 8];

    // stage K/V tile 0
    const unsigned short* kbase = qkvn + (size_t)(b * 2048 + rs) * 1152 + cs;  // + kb*64*1152
    const unsigned short* vbase = vT + (size_t)(b * 64 + rs) * 2048 + cs;      // + kb*64
    *(uint4*)&Ks[0][rs][cs]  = *(const uint4*)(kbase);
    *(uint4*)&Vts[0][rs][cs] = *(const uint4*)(vbase);
    __syncthreads();  // KV0 visible; all Q-frag reads done -> PQ reusable as P

    s16x8 ones;
#pragma unroll
    for (int e = 0; e < 8; ++e) ones[e] = (short)0x3F80;  // bf16 1.0

    f32x4 Oacc[4];
    f32x4 lacc = {0.f, 0.f, 0.f, 0.f};
#pragma unroll
    for (int nt = 0; nt < 4; ++nt) Oacc[nt] = (f32x4){0.f, 0.f, 0.f, 0.f};

    const int qglob = qb * 64 + wq * 16 + col;    // this lane's q row (fixed)
    const int kloc0 = quad * 4;                   // + nt*16 + r = local k row

    for (int kb = 0; kb <= qb; ++kb) {
        const int p = kb & 1;
        uint4 kreg, vreg;
        if (kb < qb) {  // issue next tile's global loads before compute
            kreg = *(const uint4*)(kbase + (size_t)(kb + 1) * 64 * 1152);
            vreg = *(const uint4*)(vbase + (kb + 1) * 64);
        }
        const bool diag = (kb == qb);

        // S^T = K (Q/8)^T per k-tile nt -> mask -> exp -> packed P^T write [q][k]
#pragma unroll
        for (int nt = 0; nt < 4; ++nt) {
            s16x8 kf0 = *(const s16x8*)&Ks[p][nt * 16 + col][quad * 8];
            s16x8 kf1 = *(const s16x8*)&Ks[p][nt * 16 + col][32 + quad * 8];
            f32x4 z = (f32x4){0.f, 0.f, 0.f, 0.f};
            z = MFMA16(kf0, qf0, z);   // A=K, B=Q  ->  S^T[k][q]
            z = MFMA16(kf1, qf1, z);
            ushort4 pk;
            unsigned short* pp = (unsigned short*)&pk;
#pragma unroll
            for (int r = 0; r < 4; ++r) {
                float sv = z[r];
                if (diag && (kb * 64 + nt * 16 + kloc0 + r > qglob)) sv = -1e30f;
                pp[r] = f2bf(__expf(sv - 12.0f));
            }
            *(ushort4*)&PQ[w][col][nt * 16 + kloc0] = pk;  // 8B packed write, k-contig
        }

        const s16x8 pf0 = *(const s16x8*)&PQ[w][col][quad * 8];        // B: P[q=col][k]
        const s16x8 pf1 = *(const s16x8*)&PQ[w][col][32 + quad * 8];
        lacc = MFMA16(ones, pf0, lacc);   // D[*][q] = l[q]
        lacc = MFMA16(ones, pf1, lacc);
#pragma unroll
        for (int nt = 0; nt < 4; ++nt) {
            s16x8 vf0 = *(const s16x8*)&Vts[p][nt * 16 + col][quad * 8];
            s16x8 vf1 = *(const s16x8*)&Vts[p][nt * 16 + col][32 + quad * 8];
            Oacc[nt] = MFMA16(vf0, pf0, Oacc[nt]);   // A=V^T, B=P^T -> O^T[d][q]
            Oacc[nt] = MFMA16(vf1, pf1, Oacc[nt]);
        }

        if (kb < qb) {  // LDS-write prefetched tile into the other buffer
            *(uint4*)&Ks[p ^ 1][rs][cs]  = kreg;
            *(uint4*)&Vts[p ^ 1][rs][cs] = vreg;
        }
        __syncthreads();  // ONE barrier per iter
    }

    // epilogue: lane holds O[q=col][d=nt*16+quad*4+r]; l = lacc[0] (rows identical)
    const int h = hp * 2 + hl;
    const float inv = 1.0f / lacc[0];
    const size_t base = (((size_t)b * 2048 + qglob) * 16 + h) * 64 + kloc0;
#pragma unroll
    for (int nt = 0; nt < 4; ++nt) {
        ushort4 ov;
        unsigned short* op = (unsigned short*)&ov;
#pragma unroll
        for (int r = 0; r < 4; ++r) op[r] = f2bf(Oacc[nt][r] * inv);
        *(ushort4*)&obuf[base + nt * 16] = ov;  // 8B packed store, d-contig
    }
}

// ---------- launch ----------
extern "C" void kernel_launch(void* const* d_in, const int* in_sizes, int n_in,
                              void* d_out, int out_size, void* d_ws, size_t ws_size,
                              hipStream_t stream) {
    (void)in_sizes; (void)n_in; (void)out_size; (void)ws_size;
    const float* x     = (const float*)d_in[0];  // (2,2048,1024) fp32
    const float* Wqkv  = (const float*)d_in[1];  // (1152,1024)  fp32
    const float* gamma = (const float*)d_in[2];  // (1152,)      fp32
    const float* beta  = (const float*)d_in[3];  // (1152,)      fp32
    const float* Wfc   = (const float*)d_in[4];  // (1024,1024)  fp32
    float* out = (float*)d_out;                  // (2,2048,1024) fp32

    // ws >= 22,806,528 B (proven in round 5)
    char* ws = (char*)d_ws;
    unsigned short* xb   = (unsigned short*)ws;               // 8,388,608
    unsigned short* Wqb  = (unsigned short*)(ws + 8388608);   // 2,359,296
    unsigned short* Wfb  = (unsigned short*)(ws + 10747904);  // 2,097,152
    unsigned short* qkvn = (unsigned short*)(ws + 12845056);  // 9,437,184
    unsigned short* vT   = (unsigned short*)(ws + 22282240);  //   524,288
    unsigned short* abuf = (unsigned short*)ws;               // alias xb (dead after gemm1)

    cvt_all<<<dim3(3136), 256, 0, stream>>>(x, Wqkv, Wfc, xb, Wqb, Wfb);
    gemm_mn<false><<<dim3(32, 18), 256, 0, stream>>>(xb, Wqb, qkvn, 1024, 1152);
    ln_row<<<dim3(4096), 64, 0, stream>>>(qkvn, gamma, beta, vT);
    attn_kernel<<<dim3(16, 32), 512, 0, stream>>>(qkvn, vT, abuf);
    gemm_mn<true><<<dim3(32, 16), 256, 0, stream>>>(abuf, Wfb, out, 1024, 1024);
}

// Round 15
// 167.928 us; speedup vs baseline: 1.0323x; 1.0323x over previous
//
#include <hip/hip_runtime.h>
#include <stdint.h>

typedef __attribute__((ext_vector_type(8))) short s16x8;
typedef __attribute__((ext_vector_type(4))) float f32x4;

#define MFMA16(a, b, c) __builtin_amdgcn_mfma_f32_16x16x32_bf16((a), (b), (c), 0, 0, 0)

// ---------- helpers ----------
__device__ __forceinline__ unsigned short f2bf(float f) {
    unsigned int u = __float_as_uint(f);
    return (unsigned short)((u + 0x7FFFu + ((u >> 16) & 1u)) >> 16);
}
__device__ __forceinline__ float bf2f(unsigned short h) {
    return __uint_as_float(((unsigned int)h) << 16);
}
__device__ __forceinline__ void cvt8(unsigned short* dst, const float* src) {
    const float4 f0 = *(const float4*)(src);
    const float4 f1 = *(const float4*)(src + 4);
    s16x8 v;
    v[0] = (short)f2bf(f0.x); v[1] = (short)f2bf(f0.y);
    v[2] = (short)f2bf(f0.z); v[3] = (short)f2bf(f0.w);
    v[4] = (short)f2bf(f1.x); v[5] = (short)f2bf(f1.y);
    v[6] = (short)f2bf(f1.z); v[7] = (short)f2bf(f1.w);
    *(s16x8*)dst = v;
}
// async global->LDS DMA, 16 B/lane; LDS base wave-uniform, lane i -> base+i*16.
__device__ __forceinline__ void gl_lds16(const unsigned short* g, unsigned short* l) {
    __builtin_amdgcn_global_load_lds(
        (const __attribute__((address_space(1))) unsigned int*)g,
        (__attribute__((address_space(3))) unsigned int*)l,
        16, 0, 0);
}

// ---------- merged fp32 -> bf16 convert for x / Wqkv / Wfc (one launch) ----------
__global__ __launch_bounds__(256) void cvt_all(const float* __restrict__ x,
                                               const float* __restrict__ wq,
                                               const float* __restrict__ wf,
                                               unsigned short* __restrict__ xb,
                                               unsigned short* __restrict__ wqb,
                                               unsigned short* __restrict__ wfb) {
    const int blk = blockIdx.x;  // 0..3135
    const float* src;
    unsigned short* dst;
    int base;
    if (blk < 2048)      { src = x;  dst = xb;  base = blk; }
    else if (blk < 2624) { src = wq; dst = wqb; base = blk - 2048; }
    else                 { src = wf; dst = wfb; base = blk - 2624; }
    const int i = (base * 256 + threadIdx.x) * 8;
    cvt8(&dst[i], &src[i]);
}

// ---------- GEMM 128(M)x64(N), double-buffered DMA staging (r13) ----------
template <bool OUT_F32>
__global__ __launch_bounds__(256) void gemm_mn(const unsigned short* __restrict__ A,
                                               const unsigned short* __restrict__ Bw,
                                               void* __restrict__ Cout, int K, int N) {
    const int bm = blockIdx.x, bn = blockIdx.y;
    const int t = threadIdx.x;
    const int lane = t & 63, w = t >> 6;
    const int quad = lane >> 4, col = lane & 15;
    const int wm = (w >> 1) * 64, wn = (w & 1) * 32;

    __shared__ alignas(16) unsigned short As[2][128 * 64];  // 2 x 16 KB, unpadded
    __shared__ alignas(16) unsigned short Bs[2][64 * 64];   // 2 x  8 KB, unpadded

    f32x4 acc[4][2];
#pragma unroll
    for (int i = 0; i < 4; ++i)
#pragma unroll
        for (int j = 0; j < 2; ++j) acc[i][j] = (f32x4){0.f, 0.f, 0.f, 0.f};

    const int lrow = lane >> 3;       // 0..7
    const int lcol = (lane & 7) * 8;  // 0..56 shorts
    const unsigned short* Ap = A + (size_t)(bm * 128 + w * 8 + lrow) * K + lcol;
    const unsigned short* Bp = Bw + (size_t)(bn * 64 + w * 8 + lrow) * K + lcol;

    // prime tile 0 into buffer 0
#pragma unroll
    for (int j = 0; j < 4; ++j)
        gl_lds16(Ap + (size_t)(j * 32) * K, &As[0][(j * 32 + w * 8) * 64]);
#pragma unroll
    for (int j = 0; j < 2; ++j)
        gl_lds16(Bp + (size_t)(j * 32) * K, &Bs[0][(j * 32 + w * 8) * 64]);
    __syncthreads();  // drain: tile 0 visible

    for (int k0 = 0; k0 < K; k0 += 64) {
        const int p = (k0 >> 6) & 1;
        if (k0 + 64 < K) {  // stream next tile into the other buffer (no drain)
#pragma unroll
            for (int j = 0; j < 4; ++j)
                gl_lds16(Ap + (size_t)(j * 32) * K + k0 + 64, &As[p ^ 1][(j * 32 + w * 8) * 64]);
#pragma unroll
            for (int j = 0; j < 2; ++j)
                gl_lds16(Bp + (size_t)(j * 32) * K + k0 + 64, &Bs[p ^ 1][(j * 32 + w * 8) * 64]);
        }
#pragma unroll
        for (int s = 0; s < 2; ++s) {
            s16x8 af[4], bfr[2];
#pragma unroll
            for (int i = 0; i < 4; ++i)
                af[i] = *(const s16x8*)&As[p][(wm + i * 16 + col) * 64 + s * 32 + quad * 8];
#pragma unroll
            for (int j = 0; j < 2; ++j)
                bfr[j] = *(const s16x8*)&Bs[p][(wn + j * 16 + col) * 64 + s * 32 + quad * 8];
#pragma unroll
            for (int i = 0; i < 4; ++i)
#pragma unroll
                for (int j = 0; j < 2; ++j)
                    acc[i][j] = MFMA16(af[i], bfr[j], acc[i][j]);
        }
        __syncthreads();
    }
    const int rowb = bm * 128 + wm + quad * 4;
    const int colb = bn * 64 + wn + col;
#pragma unroll
    for (int i = 0; i < 4; ++i)
#pragma unroll
        for (int j = 0; j < 2; ++j)
#pragma unroll
            for (int r = 0; r < 4; ++r) {
                size_t off = (size_t)(rowb + i * 16 + r) * N + colb + j * 16;
                if (OUT_F32) ((float*)Cout)[off] = acc[i][j][r];
                else ((unsigned short*)Cout)[off] = f2bf(acc[i][j][r]);
            }
}

// ---------- LayerNorm over 1152, one WAVE per row (r13) ----------
__global__ __launch_bounds__(64) void ln_row(unsigned short* __restrict__ qkvn,
                                             const float* __restrict__ gamma,
                                             const float* __restrict__ beta,
                                             unsigned short* __restrict__ vT) {
    const int row = blockIdx.x;  // b*2048 + l
    const int b = row >> 11, l = row & 2047;
    unsigned short* rp = qkvn + (size_t)row * 1152;
    const int lane = threadIdx.x;

    s16x8 v0 = *(const s16x8*)&rp[lane * 8];
    s16x8 v1 = *(const s16x8*)&rp[512 + lane * 8];
    unsigned int v2u = *(const unsigned int*)&rp[1024 + lane * 2];

    float f0[8], f1[8], f2[2];
    float s = 0.f, s2 = 0.f;
#pragma unroll
    for (int e = 0; e < 8; ++e) {
        f0[e] = bf2f((unsigned short)v0[e]);
        f1[e] = bf2f((unsigned short)v1[e]);
        s += f0[e] + f1[e];
        s2 += f0[e] * f0[e] + f1[e] * f1[e];
    }
    f2[0] = bf2f((unsigned short)(v2u & 0xFFFF));
    f2[1] = bf2f((unsigned short)(v2u >> 16));
    s += f2[0] + f2[1];
    s2 += f2[0] * f2[0] + f2[1] * f2[1];

#pragma unroll
    for (int off = 1; off < 64; off <<= 1) {
        s += __shfl_xor(s, off);
        s2 += __shfl_xor(s2, off);
    }
    const float mu = s * (1.0f / 1152.0f);
    float var = s2 * (1.0f / 1152.0f) - mu * mu;
    var = fmaxf(var, 0.0f);
    const float rstd = rsqrtf(var + 1e-5f);

    {
        s16x8 o;
#pragma unroll
        for (int e = 0; e < 8; ++e)
            o[e] = (short)f2bf((f0[e] - mu) * rstd * gamma[lane * 8 + e] + beta[lane * 8 + e]);
        *(s16x8*)&rp[lane * 8] = o;
        if (lane >= 8 && lane < 16) {  // v head (cols 64..127) -> transposed copy
            const int d0 = lane * 8 - 64;
#pragma unroll
            for (int e = 0; e < 8; ++e)
                vT[((size_t)(b * 64 + d0 + e)) * 2048 + l] = (unsigned short)o[e];
        }
    }
    {
        s16x8 o;
#pragma unroll
        for (int e = 0; e < 8; ++e)
            o[e] = (short)f2bf((f1[e] - mu) * rstd * gamma[512 + lane * 8 + e] + beta[512 + lane * 8 + e]);
        *(s16x8*)&rp[512 + lane * 8] = o;
    }
    {
        unsigned short o0 = f2bf((f2[0] - mu) * rstd * gamma[1024 + lane * 2] + beta[1024 + lane * 2]);
        unsigned short o1 = f2bf((f2[1] - mu) * rstd * gamma[1025 + lane * 2] + beta[1025 + lane * 2]);
        *(unsigned int*)&rp[1024 + lane * 2] = ((unsigned int)o1 << 16) | o0;
    }
}

// ---------- Flash-style causal multi-query attention (r14 transposed path) ----------
// ONLY change vs r14: qb mapping pairs complementary tiles onto the same CU.
// Linear dispatch: block ids 0..255 and 256..511 land on CUs 0..255 in the same
// order (2x oversubscription, all co-resident). Old qb=31-y gave CU c iter
// totals 48-2*(c/16) (48 on CU0 vs 18 on CU255 -> 1.45x makespan skew; matches
// Occupancy 24%). New mapping: first half qb=31-y (large, starts first), second
// half qb=y-16 -> every CU totals exactly 33 iters.
__global__ __launch_bounds__(512) void attn_kernel(const unsigned short* __restrict__ qkvn,
                                                   const unsigned short* __restrict__ vT,
                                                   unsigned short* __restrict__ obuf) {
    const int b = blockIdx.x >> 3, hp = blockIdx.x & 7;
    const int yy = blockIdx.y;
    const int qb = (yy < 16) ? (31 - yy) : (yy - 16);  // CU-paired: (31-a) + a = 33 iters/CU
    const int t = threadIdx.x;
    const int lane = t & 63, w = t >> 6;
    const int quad = lane >> 4, col = lane & 15;
    const int hl = w >> 2, wq = w & 3;   // head-local, wave-in-head

    __shared__ alignas(16) unsigned short Ks[2][64][72];
    __shared__ alignas(16) unsigned short Vts[2][64][72];   // [d][j]
    __shared__ alignas(16) unsigned short PQ[8][16][72];    // Q-stage, then per-wave P^T as [q][k]

    unsigned short(*Qs)[72] = (unsigned short(*)[72])PQ;    // view as [128][72]

    const int rs = t >> 3;        // 0..63
    const int cs = (t & 7) * 8;   // 0..56

    // stage Q for both heads, pre-scaled by 1/8 (exact in bf16)
#pragma unroll
    for (int hh = 0; hh < 2; ++hh) {
        const unsigned short* qsrc =
            qkvn + (size_t)(b * 2048 + qb * 64 + rs) * 1152 + 128 + (hp * 2 + hh) * 64 + cs;
        s16x8 v = *(const s16x8*)qsrc;
#pragma unroll
        for (int e = 0; e < 8; ++e)
            v[e] = (short)f2bf(bf2f((unsigned short)v[e]) * 0.125f);
        *(s16x8*)&Qs[hh * 64 + rs][cs] = v;
    }
    __syncthreads();
    const s16x8 qf0 = *(const s16x8*)&Qs[hl * 64 + wq * 16 + col][quad * 8];
    const s16x8 qf1 = *(const s16x8*)&Qs[hl * 64 + wq * 16 + col][32 + quad * 8];

    // stage K/V tile 0
    const unsigned short* kbase = qkvn + (size_t)(b * 2048 + rs) * 1152 + cs;  // + kb*64*1152
    const unsigned short* vbase = vT + (size_t)(b * 64 + rs) * 2048 + cs;      // + kb*64
    *(uint4*)&Ks[0][rs][cs]  = *(const uint4*)(kbase);
    *(uint4*)&Vts[0][rs][cs] = *(const uint4*)(vbase);
    __syncthreads();  // KV0 visible; all Q-frag reads done -> PQ reusable as P

    s16x8 ones;
#pragma unroll
    for (int e = 0; e < 8; ++e) ones[e] = (short)0x3F80;  // bf16 1.0

    f32x4 Oacc[4];
    f32x4 lacc = {0.f, 0.f, 0.f, 0.f};
#pragma unroll
    for (int nt = 0; nt < 4; ++nt) Oacc[nt] = (f32x4){0.f, 0.f, 0.f, 0.f};

    const int qglob = qb * 64 + wq * 16 + col;    // this lane's q row (fixed)
    const int kloc0 = quad * 4;                   // + nt*16 + r = local k row

    for (int kb = 0; kb <= qb; ++kb) {
        const int p = kb & 1;
        uint4 kreg, vreg;
        if (kb < qb) {  // issue next tile's global loads before compute
            kreg = *(const uint4*)(kbase + (size_t)(kb + 1) * 64 * 1152);
            vreg = *(const uint4*)(vbase + (kb + 1) * 64);
        }
        const bool diag = (kb == qb);

        // S^T = K (Q/8)^T per k-tile nt -> mask -> exp -> packed P^T write [q][k]
#pragma unroll
        for (int nt = 0; nt < 4; ++nt) {
            s16x8 kf0 = *(const s16x8*)&Ks[p][nt * 16 + col][quad * 8];
            s16x8 kf1 = *(const s16x8*)&Ks[p][nt * 16 + col][32 + quad * 8];
            f32x4 z = (f32x4){0.f, 0.f, 0.f, 0.f};
            z = MFMA16(kf0, qf0, z);   // A=K, B=Q  ->  S^T[k][q]
            z = MFMA16(kf1, qf1, z);
            ushort4 pk;
            unsigned short* pp = (unsigned short*)&pk;
#pragma unroll
            for (int r = 0; r < 4; ++r) {
                float sv = z[r];
                if (diag && (kb * 64 + nt * 16 + kloc0 + r > qglob)) sv = -1e30f;
                pp[r] = f2bf(__expf(sv - 12.0f));
            }
            *(ushort4*)&PQ[w][col][nt * 16 + kloc0] = pk;  // 8B packed write, k-contig
        }

        const s16x8 pf0 = *(const s16x8*)&PQ[w][col][quad * 8];        // B: P[q=col][k]
        const s16x8 pf1 = *(const s16x8*)&PQ[w][col][32 + quad * 8];
        lacc = MFMA16(ones, pf0, lacc);   // D[*][q] = l[q]
        lacc = MFMA16(ones, pf1, lacc);
#pragma unroll
        for (int nt = 0; nt < 4; ++nt) {
            s16x8 vf0 = *(const s16x8*)&Vts[p][nt * 16 + col][quad * 8];
            s16x8 vf1 = *(const s16x8*)&Vts[p][nt * 16 + col][32 + quad * 8];
            Oacc[nt] = MFMA16(vf0, pf0, Oacc[nt]);   // A=V^T, B=P^T -> O^T[d][q]
            Oacc[nt] = MFMA16(vf1, pf1, Oacc[nt]);
        }

        if (kb < qb) {  // LDS-write prefetched tile into the other buffer
            *(uint4*)&Ks[p ^ 1][rs][cs]  = kreg;
            *(uint4*)&Vts[p ^ 1][rs][cs] = vreg;
        }
        __syncthreads();  // ONE barrier per iter
    }

    // epilogue: lane holds O[q=col][d=nt*16+quad*4+r]; l = lacc[0] (rows identical)
    const int h = hp * 2 + hl;
    const float inv = 1.0f / lacc[0];
    const size_t base = (((size_t)b * 2048 + qglob) * 16 + h) * 64 + kloc0;
#pragma unroll
    for (int nt = 0; nt < 4; ++nt) {
        ushort4 ov;
        unsigned short* op = (unsigned short*)&ov;
#pragma unroll
        for (int r = 0; r < 4; ++r) op[r] = f2bf(Oacc[nt][r] * inv);
        *(ushort4*)&obuf[base + nt * 16] = ov;  // 8B packed store, d-contig
    }
}

// ---------- launch ----------
extern "C" void kernel_launch(void* const* d_in, const int* in_sizes, int n_in,
                              void* d_out, int out_size, void* d_ws, size_t ws_size,
                              hipStream_t stream) {
    (void)in_sizes; (void)n_in; (void)out_size; (void)ws_size;
    const float* x     = (const float*)d_in[0];  // (2,2048,1024) fp32
    const float* Wqkv  = (const float*)d_in[1];  // (1152,1024)  fp32
    const float* gamma = (const float*)d_in[2];  // (1152,)      fp32
    const float* beta  = (const float*)d_in[3];  // (1152,)      fp32
    const float* Wfc   = (const float*)d_in[4];  // (1024,1024)  fp32
    float* out = (float*)d_out;                  // (2,2048,1024) fp32

    // ws >= 22,806,528 B (proven in round 5)
    char* ws = (char*)d_ws;
    unsigned short* xb   = (unsigned short*)ws;               // 8,388,608
    unsigned short* Wqb  = (unsigned short*)(ws + 8388608);   // 2,359,296
    unsigned short* Wfb  = (unsigned short*)(ws + 10747904);  // 2,097,152
    unsigned short* qkvn = (unsigned short*)(ws + 12845056);  // 9,437,184
    unsigned short* vT   = (unsigned short*)(ws + 22282240);  //   524,288
    unsigned short* abuf = (unsigned short*)ws;               // alias xb (dead after gemm1)

    cvt_all<<<dim3(3136), 256, 0, stream>>>(x, Wqkv, Wfc, xb, Wqb, Wfb);
    gemm_mn<false><<<dim3(32, 18), 256, 0, stream>>>(xb, Wqb, qkvn, 1024, 1152);
    ln_row<<<dim3(4096), 64, 0, stream>>>(qkvn, gamma, beta, vT);
    attn_kernel<<<dim3(16, 32), 512, 0, stream>>>(qkvn, vT, abuf);
    gemm_mn<true><<<dim3(32, 16), 256, 0, stream>>>(abuf, Wfb, out, 1024, 1024);
}

// Round 16
// 164.667 us; speedup vs baseline: 1.0528x; 1.0198x over previous
//
#include <hip/hip_runtime.h>
#include <stdint.h>

typedef __attribute__((ext_vector_type(8))) short s16x8;
typedef __attribute__((ext_vector_type(4))) float f32x4;

#define MFMA16(a, b, c) __builtin_amdgcn_mfma_f32_16x16x32_bf16((a), (b), (c), 0, 0, 0)

// ---------- helpers ----------
__device__ __forceinline__ unsigned short f2bf(float f) {
    unsigned int u = __float_as_uint(f);
    return (unsigned short)((u + 0x7FFFu + ((u >> 16) & 1u)) >> 16);
}
__device__ __forceinline__ float bf2f(unsigned short h) {
    return __uint_as_float(((unsigned int)h) << 16);
}
__device__ __forceinline__ void cvt8(unsigned short* dst, const float* src) {
    const float4 f0 = *(const float4*)(src);
    const float4 f1 = *(const float4*)(src + 4);
    s16x8 v;
    v[0] = (short)f2bf(f0.x); v[1] = (short)f2bf(f0.y);
    v[2] = (short)f2bf(f0.z); v[3] = (short)f2bf(f0.w);
    v[4] = (short)f2bf(f1.x); v[5] = (short)f2bf(f1.y);
    v[6] = (short)f2bf(f1.z); v[7] = (short)f2bf(f1.w);
    *(s16x8*)dst = v;
}
// async global->LDS DMA, 16 B/lane; LDS base wave-uniform, lane i -> base+i*16.
__device__ __forceinline__ void gl_lds16(const unsigned short* g, unsigned short* l) {
    __builtin_amdgcn_global_load_lds(
        (const __attribute__((address_space(1))) unsigned int*)g,
        (__attribute__((address_space(3))) unsigned int*)l,
        16, 0, 0);
}

// ---------- merged fp32 -> bf16 convert for x / Wqkv / Wfc (one launch) ----------
__global__ __launch_bounds__(256) void cvt_all(const float* __restrict__ x,
                                               const float* __restrict__ wq,
                                               const float* __restrict__ wf,
                                               unsigned short* __restrict__ xb,
                                               unsigned short* __restrict__ wqb,
                                               unsigned short* __restrict__ wfb) {
    const int blk = blockIdx.x;  // 0..3135
    const float* src;
    unsigned short* dst;
    int base;
    if (blk < 2048)      { src = x;  dst = xb;  base = blk; }
    else if (blk < 2624) { src = wq; dst = wqb; base = blk - 2048; }
    else                 { src = wf; dst = wfb; base = blk - 2624; }
    const int i = (base * 256 + threadIdx.x) * 8;
    cvt8(&dst[i], &src[i]);
}

// ---------- GEMM 128(M)x64(N), double-buffered DMA staging (r13) ----------
template <bool OUT_F32>
__global__ __launch_bounds__(256) void gemm_mn(const unsigned short* __restrict__ A,
                                               const unsigned short* __restrict__ Bw,
                                               void* __restrict__ Cout, int K, int N) {
    const int bm = blockIdx.x, bn = blockIdx.y;
    const int t = threadIdx.x;
    const int lane = t & 63, w = t >> 6;
    const int quad = lane >> 4, col = lane & 15;
    const int wm = (w >> 1) * 64, wn = (w & 1) * 32;

    __shared__ alignas(16) unsigned short As[2][128 * 64];  // 2 x 16 KB, unpadded
    __shared__ alignas(16) unsigned short Bs[2][64 * 64];   // 2 x  8 KB, unpadded

    f32x4 acc[4][2];
#pragma unroll
    for (int i = 0; i < 4; ++i)
#pragma unroll
        for (int j = 0; j < 2; ++j) acc[i][j] = (f32x4){0.f, 0.f, 0.f, 0.f};

    const int lrow = lane >> 3;       // 0..7
    const int lcol = (lane & 7) * 8;  // 0..56 shorts
    const unsigned short* Ap = A + (size_t)(bm * 128 + w * 8 + lrow) * K + lcol;
    const unsigned short* Bp = Bw + (size_t)(bn * 64 + w * 8 + lrow) * K + lcol;

    // prime tile 0 into buffer 0
#pragma unroll
    for (int j = 0; j < 4; ++j)
        gl_lds16(Ap + (size_t)(j * 32) * K, &As[0][(j * 32 + w * 8) * 64]);
#pragma unroll
    for (int j = 0; j < 2; ++j)
        gl_lds16(Bp + (size_t)(j * 32) * K, &Bs[0][(j * 32 + w * 8) * 64]);
    __syncthreads();  // drain: tile 0 visible

    for (int k0 = 0; k0 < K; k0 += 64) {
        const int p = (k0 >> 6) & 1;
        if (k0 + 64 < K) {  // stream next tile into the other buffer (no drain)
#pragma unroll
            for (int j = 0; j < 4; ++j)
                gl_lds16(Ap + (size_t)(j * 32) * K + k0 + 64, &As[p ^ 1][(j * 32 + w * 8) * 64]);
#pragma unroll
            for (int j = 0; j < 2; ++j)
                gl_lds16(Bp + (size_t)(j * 32) * K + k0 + 64, &Bs[p ^ 1][(j * 32 + w * 8) * 64]);
        }
#pragma unroll
        for (int s = 0; s < 2; ++s) {
            s16x8 af[4], bfr[2];
#pragma unroll
            for (int i = 0; i < 4; ++i)
                af[i] = *(const s16x8*)&As[p][(wm + i * 16 + col) * 64 + s * 32 + quad * 8];
#pragma unroll
            for (int j = 0; j < 2; ++j)
                bfr[j] = *(const s16x8*)&Bs[p][(wn + j * 16 + col) * 64 + s * 32 + quad * 8];
#pragma unroll
            for (int i = 0; i < 4; ++i)
#pragma unroll
                for (int j = 0; j < 2; ++j)
                    acc[i][j] = MFMA16(af[i], bfr[j], acc[i][j]);
        }
        __syncthreads();
    }
    const int rowb = bm * 128 + wm + quad * 4;
    const int colb = bn * 64 + wn + col;
#pragma unroll
    for (int i = 0; i < 4; ++i)
#pragma unroll
        for (int j = 0; j < 2; ++j)
#pragma unroll
            for (int r = 0; r < 4; ++r) {
                size_t off = (size_t)(rowb + i * 16 + r) * N + colb + j * 16;
                if (OUT_F32) ((float*)Cout)[off] = acc[i][j][r];
                else ((unsigned short*)Cout)[off] = f2bf(acc[i][j][r]);
            }
}

// ---------- LayerNorm over 1152, one WAVE per row (r13) ----------
__global__ __launch_bounds__(64) void ln_row(unsigned short* __restrict__ qkvn,
                                             const float* __restrict__ gamma,
                                             const float* __restrict__ beta,
                                             unsigned short* __restrict__ vT) {
    const int row = blockIdx.x;  // b*2048 + l
    const int b = row >> 11, l = row & 2047;
    unsigned short* rp = qkvn + (size_t)row * 1152;
    const int lane = threadIdx.x;

    s16x8 v0 = *(const s16x8*)&rp[lane * 8];
    s16x8 v1 = *(const s16x8*)&rp[512 + lane * 8];
    unsigned int v2u = *(const unsigned int*)&rp[1024 + lane * 2];

    float f0[8], f1[8], f2[2];
    float s = 0.f, s2 = 0.f;
#pragma unroll
    for (int e = 0; e < 8; ++e) {
        f0[e] = bf2f((unsigned short)v0[e]);
        f1[e] = bf2f((unsigned short)v1[e]);
        s += f0[e] + f1[e];
        s2 += f0[e] * f0[e] + f1[e] * f1[e];
    }
    f2[0] = bf2f((unsigned short)(v2u & 0xFFFF));
    f2[1] = bf2f((unsigned short)(v2u >> 16));
    s += f2[0] + f2[1];
    s2 += f2[0] * f2[0] + f2[1] * f2[1];

#pragma unroll
    for (int off = 1; off < 64; off <<= 1) {
        s += __shfl_xor(s, off);
        s2 += __shfl_xor(s2, off);
    }
    const float mu = s * (1.0f / 1152.0f);
    float var = s2 * (1.0f / 1152.0f) - mu * mu;
    var = fmaxf(var, 0.0f);
    const float rstd = rsqrtf(var + 1e-5f);

    {
        s16x8 o;
#pragma unroll
        for (int e = 0; e < 8; ++e)
            o[e] = (short)f2bf((f0[e] - mu) * rstd * gamma[lane * 8 + e] + beta[lane * 8 + e]);
        *(s16x8*)&rp[lane * 8] = o;
        if (lane >= 8 && lane < 16) {  // v head (cols 64..127) -> transposed copy
            const int d0 = lane * 8 - 64;
#pragma unroll
            for (int e = 0; e < 8; ++e)
                vT[((size_t)(b * 64 + d0 + e)) * 2048 + l] = (unsigned short)o[e];
        }
    }
    {
        s16x8 o;
#pragma unroll
        for (int e = 0; e < 8; ++e)
            o[e] = (short)f2bf((f1[e] - mu) * rstd * gamma[512 + lane * 8 + e] + beta[512 + lane * 8 + e]);
        *(s16x8*)&rp[512 + lane * 8] = o;
    }
    {
        unsigned short o0 = f2bf((f2[0] - mu) * rstd * gamma[1024 + lane * 2] + beta[1024 + lane * 2]);
        unsigned short o1 = f2bf((f2[1] - mu) * rstd * gamma[1025 + lane * 2] + beta[1025 + lane * 2]);
        *(unsigned int*)&rp[1024 + lane * 2] = ((unsigned int)o1 << 16) | o0;
    }
}

// ---------- Flash-style causal multi-query attention ----------
// r15 structure (transposed MFMA path, CU-paired qb, register-prefetch dbuf)
// + ONE change: K/V tiles in XOR-SWIZZLED UNPADDED [64][64] layout (r11-proven
// 0 bank conflicts) instead of padded [64][72] (measured 5.98M conflict cycles
// = ~23% of attn). Staging thread (row r, chunk c) writes LDS chunk c^(r&7);
// fragment reads use precomputed swizzled offsets (row&7 == col&7 since tile
// rows are 16-aligned).
__global__ __launch_bounds__(512) void attn_kernel(const unsigned short* __restrict__ qkvn,
                                                   const unsigned short* __restrict__ vT,
                                                   unsigned short* __restrict__ obuf) {
    const int b = blockIdx.x >> 3, hp = blockIdx.x & 7;
    const int yy = blockIdx.y;
    const int qb = (yy < 16) ? (31 - yy) : (yy - 16);  // CU-paired: (31-a)+a = 33 iters/CU
    const int t = threadIdx.x;
    const int lane = t & 63, w = t >> 6;
    const int quad = lane >> 4, col = lane & 15;
    const int hl = w >> 2, wq = w & 3;   // head-local, wave-in-head

    __shared__ alignas(16) unsigned short Ks[2][4096];   // 16 KB swizzled, unpadded
    __shared__ alignas(16) unsigned short Vts[2][4096];  // 16 KB ([d][j] swizzled)
    __shared__ alignas(16) unsigned short PQ[8][16][72]; // Q-stage, then per-wave P^T [q][k]

    unsigned short(*Qs)[72] = (unsigned short(*)[72])PQ; // view as [128][72]

    const int srow = t >> 3;                  // 0..63
    const int schunk = t & 7;                 // global 8-short chunk
    const int ldsoff = srow * 64 + (schunk ^ (srow & 7)) * 8;  // swizzled LDS addr

    // stage Q for both heads, pre-scaled by 1/8 (exact in bf16)
#pragma unroll
    for (int hh = 0; hh < 2; ++hh) {
        const unsigned short* qsrc =
            qkvn + (size_t)(b * 2048 + qb * 64 + srow) * 1152 + 128 + (hp * 2 + hh) * 64 + schunk * 8;
        s16x8 v = *(const s16x8*)qsrc;
#pragma unroll
        for (int e = 0; e < 8; ++e)
            v[e] = (short)f2bf(bf2f((unsigned short)v[e]) * 0.125f);
        *(s16x8*)&Qs[hh * 64 + srow][schunk * 8] = v;
    }
    __syncthreads();
    const s16x8 qf0 = *(const s16x8*)&Qs[hl * 64 + wq * 16 + col][quad * 8];
    const s16x8 qf1 = *(const s16x8*)&Qs[hl * 64 + wq * 16 + col][32 + quad * 8];

    // stage K/V tile 0 (global reads linear; LDS writes swizzled)
    const unsigned short* kbase = qkvn + (size_t)(b * 2048 + srow) * 1152 + schunk * 8;  // + kb*64*1152
    const unsigned short* vbase = vT + (size_t)(b * 64 + srow) * 2048 + schunk * 8;      // + kb*64
    *(uint4*)&Ks[0][ldsoff]  = *(const uint4*)(kbase);
    *(uint4*)&Vts[0][ldsoff] = *(const uint4*)(vbase);
    __syncthreads();  // KV0 visible; all Q-frag reads done -> PQ reusable as P

    // fragment byte offsets into swizzled tiles (invariant; + nt*2048 per tile)
    const int fo0 = col * 128 + ((quad ^ (col & 7)) * 16);        // k-half 0
    const int fo1 = col * 128 + (((4 + quad) ^ (col & 7)) * 16);  // k-half 1

    s16x8 ones;
#pragma unroll
    for (int e = 0; e < 8; ++e) ones[e] = (short)0x3F80;  // bf16 1.0

    f32x4 Oacc[4];
    f32x4 lacc = {0.f, 0.f, 0.f, 0.f};
#pragma unroll
    for (int nt = 0; nt < 4; ++nt) Oacc[nt] = (f32x4){0.f, 0.f, 0.f, 0.f};

    const int qglob = qb * 64 + wq * 16 + col;    // this lane's q row (fixed)
    const int kloc0 = quad * 4;                   // + nt*16 + r = local k row

    for (int kb = 0; kb <= qb; ++kb) {
        const int p = kb & 1;
        uint4 kreg, vreg;
        if (kb < qb) {  // issue next tile's global loads before compute
            kreg = *(const uint4*)(kbase + (size_t)(kb + 1) * 64 * 1152);
            vreg = *(const uint4*)(vbase + (kb + 1) * 64);
        }
        const bool diag = (kb == qb);
        const char* kb8 = (const char*)Ks[p];
        const char* vb8 = (const char*)Vts[p];

        // S^T = K (Q/8)^T per k-tile nt -> mask -> exp -> packed P^T write [q][k]
#pragma unroll
        for (int nt = 0; nt < 4; ++nt) {
            s16x8 kf0 = *(const s16x8*)(kb8 + nt * 2048 + fo0);
            s16x8 kf1 = *(const s16x8*)(kb8 + nt * 2048 + fo1);
            f32x4 z = (f32x4){0.f, 0.f, 0.f, 0.f};
            z = MFMA16(kf0, qf0, z);   // A=K, B=Q  ->  S^T[k][q]
            z = MFMA16(kf1, qf1, z);
            ushort4 pk;
            unsigned short* pp = (unsigned short*)&pk;
#pragma unroll
            for (int r = 0; r < 4; ++r) {
                float sv = z[r];
                if (diag && (kb * 64 + nt * 16 + kloc0 + r > qglob)) sv = -1e30f;
                pp[r] = f2bf(__expf(sv - 12.0f));
            }
            *(ushort4*)&PQ[w][col][nt * 16 + kloc0] = pk;  // 8B packed write, k-contig
        }

        const s16x8 pf0 = *(const s16x8*)&PQ[w][col][quad * 8];        // B: P[q=col][k]
        const s16x8 pf1 = *(const s16x8*)&PQ[w][col][32 + quad * 8];
        lacc = MFMA16(ones, pf0, lacc);   // D[*][q] = l[q]
        lacc = MFMA16(ones, pf1, lacc);
#pragma unroll
        for (int nt = 0; nt < 4; ++nt) {
            s16x8 vf0 = *(const s16x8*)(vb8 + nt * 2048 + fo0);
            s16x8 vf1 = *(const s16x8*)(vb8 + nt * 2048 + fo1);
            Oacc[nt] = MFMA16(vf0, pf0, Oacc[nt]);   // A=V^T, B=P^T -> O^T[d][q]
            Oacc[nt] = MFMA16(vf1, pf1, Oacc[nt]);
        }

        if (kb < qb) {  // LDS-write prefetched tile into the other (swizzled) buffer
            *(uint4*)&Ks[p ^ 1][ldsoff]  = kreg;
            *(uint4*)&Vts[p ^ 1][ldsoff] = vreg;
        }
        __syncthreads();  // ONE barrier per iter
    }

    // epilogue: lane holds O[q=col][d=nt*16+quad*4+r]; l = lacc[0] (rows identical)
    const int h = hp * 2 + hl;
    const float inv = 1.0f / lacc[0];
    const size_t base = (((size_t)b * 2048 + qglob) * 16 + h) * 64 + kloc0;
#pragma unroll
    for (int nt = 0; nt < 4; ++nt) {
        ushort4 ov;
        unsigned short* op = (unsigned short*)&ov;
#pragma unroll
        for (int r = 0; r < 4; ++r) op[r] = f2bf(Oacc[nt][r] * inv);
        *(ushort4*)&obuf[base + nt * 16] = ov;  // 8B packed store, d-contig
    }
}

// ---------- launch ----------
extern "C" void kernel_launch(void* const* d_in, const int* in_sizes, int n_in,
                              void* d_out, int out_size, void* d_ws, size_t ws_size,
                              hipStream_t stream) {
    (void)in_sizes; (void)n_in; (void)out_size; (void)ws_size;
    const float* x     = (const float*)d_in[0];  // (2,2048,1024) fp32
    const float* Wqkv  = (const float*)d_in[1];  // (1152,1024)  fp32
    const float* gamma = (const float*)d_in[2];  // (1152,)      fp32
    const float* beta  = (const float*)d_in[3];  // (1152,)      fp32
    const float* Wfc   = (const float*)d_in[4];  // (1024,1024)  fp32
    float* out = (float*)d_out;                  // (2,2048,1024) fp32

    // ws >= 22,806,528 B (proven in round 5)
    char* ws = (char*)d_ws;
    unsigned short* xb   = (unsigned short*)ws;               // 8,388,608
    unsigned short* Wqb  = (unsigned short*)(ws + 8388608);   // 2,359,296
    unsigned short* Wfb  = (unsigned short*)(ws + 10747904);  // 2,097,152
    unsigned short* qkvn = (unsigned short*)(ws + 12845056);  // 9,437,184
    unsigned short* vT   = (unsigned short*)(ws + 22282240);  //   524,288
    unsigned short* abuf = (unsigned short*)ws;               // alias xb (dead after gemm1)

    cvt_all<<<dim3(3136), 256, 0, stream>>>(x, Wqkv, Wfc, xb, Wqb, Wfb);
    gemm_mn<false><<<dim3(32, 18), 256, 0, stream>>>(xb, Wqb, qkvn, 1024, 1152);
    ln_row<<<dim3(4096), 64, 0, stream>>>(qkvn, gamma, beta, vT);
    attn_kernel<<<dim3(16, 32), 512, 0, stream>>>(qkvn, vT, abuf);
    gemm_mn<true><<<dim3(32, 16), 256, 0, stream>>>(abuf, Wfb, out, 1024, 1024);
}

// Round 17
// 152.241 us; speedup vs baseline: 1.1387x; 1.0816x over previous
//
#include <hip/hip_runtime.h>
#include <stdint.h>

typedef __attribute__((ext_vector_type(8))) short s16x8;
typedef __attribute__((ext_vector_type(4))) float f32x4;

#define MFMA16(a, b, c) __builtin_amdgcn_mfma_f32_16x16x32_bf16((a), (b), (c), 0, 0, 0)

// ---------- helpers ----------
__device__ __forceinline__ unsigned short f2bf(float f) {
    unsigned int u = __float_as_uint(f);
    return (unsigned short)((u + 0x7FFFu + ((u >> 16) & 1u)) >> 16);
}
__device__ __forceinline__ float bf2f(unsigned short h) {
    return __uint_as_float(((unsigned int)h) << 16);
}
__device__ __forceinline__ void cvt8(unsigned short* dst, const float* src) {
    const float4 f0 = *(const float4*)(src);
    const float4 f1 = *(const float4*)(src + 4);
    s16x8 v;
    v[0] = (short)f2bf(f0.x); v[1] = (short)f2bf(f0.y);
    v[2] = (short)f2bf(f0.z); v[3] = (short)f2bf(f0.w);
    v[4] = (short)f2bf(f1.x); v[5] = (short)f2bf(f1.y);
    v[6] = (short)f2bf(f1.z); v[7] = (short)f2bf(f1.w);
    *(s16x8*)dst = v;
}
// async global->LDS DMA, 16 B/lane; LDS base wave-uniform, lane i -> base+i*16.
__device__ __forceinline__ void gl_lds16(const unsigned short* g, unsigned short* l) {
    __builtin_amdgcn_global_load_lds(
        (const __attribute__((address_space(1))) unsigned int*)g,
        (__attribute__((address_space(3))) unsigned int*)l,
        16, 0, 0);
}

// ---------- merged fp32 -> bf16 convert for x / Wqkv / Wfc (one launch) ----------
__global__ __launch_bounds__(256) void cvt_all(const float* __restrict__ x,
                                               const float* __restrict__ wq,
                                               const float* __restrict__ wf,
                                               unsigned short* __restrict__ xb,
                                               unsigned short* __restrict__ wqb,
                                               unsigned short* __restrict__ wfb) {
    const int blk = blockIdx.x;  // 0..3135
    const float* src;
    unsigned short* dst;
    int base;
    if (blk < 2048)      { src = x;  dst = xb;  base = blk; }
    else if (blk < 2624) { src = wq; dst = wqb; base = blk - 2048; }
    else                 { src = wf; dst = wfb; base = blk - 2624; }
    const int i = (base * 256 + threadIdx.x) * 8;
    cvt8(&dst[i], &src[i]);
}

// ---------- GEMM 128(M)x64(N), dbuf DMA staging + XOR-SWIZZLED tiles ----------
// Unpadded [row][64] tiles have row stride 128 B = the 32-bank period: the 16
// col-lanes of each fragment read hit one 4-bank group = 16-way conflict
// (~5.7x LDS throughput loss; predicted ~49us of LDS time for gemm1 -- matches
// measurement). DMA dest mapping is fixed (lane i -> base+i*16), so swizzle
// the GLOBAL SOURCE instead: staging lane (row r, slot c) loads global chunk
// c^(r&7) (same 128B segment -> still coalesced); fragment reads use chunk
// (s*4+quad)^(col&7) (row&7 == col&7: all row bases are multiples of 16).
// Same recipe as the attn kernel's r16 swizzle (absmax-identical verified).
template <bool OUT_F32>
__global__ __launch_bounds__(256) void gemm_mn(const unsigned short* __restrict__ A,
                                               const unsigned short* __restrict__ Bw,
                                               void* __restrict__ Cout, int K, int N) {
    const int bm = blockIdx.x, bn = blockIdx.y;
    const int t = threadIdx.x;
    const int lane = t & 63, w = t >> 6;
    const int quad = lane >> 4, col = lane & 15;
    const int wm = (w >> 1) * 64, wn = (w & 1) * 32;

    __shared__ alignas(16) unsigned short As[2][128 * 64];  // 2 x 16 KB, unpadded swizzled
    __shared__ alignas(16) unsigned short Bs[2][64 * 64];   // 2 x  8 KB, unpadded swizzled

    f32x4 acc[4][2];
#pragma unroll
    for (int i = 0; i < 4; ++i)
#pragma unroll
        for (int j = 0; j < 2; ++j) acc[i][j] = (f32x4){0.f, 0.f, 0.f, 0.f};

    const int lrow = lane >> 3;                      // 0..7
    const int lcol = ((lane & 7) ^ lrow) * 8;        // swizzled global chunk
    const unsigned short* Ap = A + (size_t)(bm * 128 + w * 8 + lrow) * K + lcol;
    const unsigned short* Bp = Bw + (size_t)(bn * 64 + w * 8 + lrow) * K + lcol;

    // prime tile 0 into buffer 0
#pragma unroll
    for (int j = 0; j < 4; ++j)
        gl_lds16(Ap + (size_t)(j * 32) * K, &As[0][(j * 32 + w * 8) * 64]);
#pragma unroll
    for (int j = 0; j < 2; ++j)
        gl_lds16(Bp + (size_t)(j * 32) * K, &Bs[0][(j * 32 + w * 8) * 64]);
    __syncthreads();  // drain: tile 0 visible

    // swizzled fragment chunk offsets (shorts): row*64 + ((s*4+quad)^(col&7))*8
    const int c7 = col & 7;
    const int fs0 = ((0 * 4 + quad) ^ c7) * 8;
    const int fs1 = ((1 * 4 + quad) ^ c7) * 8;

    for (int k0 = 0; k0 < K; k0 += 64) {
        const int p = (k0 >> 6) & 1;
        if (k0 + 64 < K) {  // stream next tile into the other buffer (no drain)
#pragma unroll
            for (int j = 0; j < 4; ++j)
                gl_lds16(Ap + (size_t)(j * 32) * K + k0 + 64, &As[p ^ 1][(j * 32 + w * 8) * 64]);
#pragma unroll
            for (int j = 0; j < 2; ++j)
                gl_lds16(Bp + (size_t)(j * 32) * K + k0 + 64, &Bs[p ^ 1][(j * 32 + w * 8) * 64]);
        }
#pragma unroll
        for (int s = 0; s < 2; ++s) {
            const int fs = s ? fs1 : fs0;
            s16x8 af[4], bfr[2];
#pragma unroll
            for (int i = 0; i < 4; ++i)
                af[i] = *(const s16x8*)&As[p][(wm + i * 16 + col) * 64 + fs];
#pragma unroll
            for (int j = 0; j < 2; ++j)
                bfr[j] = *(const s16x8*)&Bs[p][(wn + j * 16 + col) * 64 + fs];
#pragma unroll
            for (int i = 0; i < 4; ++i)
#pragma unroll
                for (int j = 0; j < 2; ++j)
                    acc[i][j] = MFMA16(af[i], bfr[j], acc[i][j]);
        }
        __syncthreads();
    }
    const int rowb = bm * 128 + wm + quad * 4;
    const int colb = bn * 64 + wn + col;
#pragma unroll
    for (int i = 0; i < 4; ++i)
#pragma unroll
        for (int j = 0; j < 2; ++j)
#pragma unroll
            for (int r = 0; r < 4; ++r) {
                size_t off = (size_t)(rowb + i * 16 + r) * N + colb + j * 16;
                if (OUT_F32) ((float*)Cout)[off] = acc[i][j][r];
                else ((unsigned short*)Cout)[off] = f2bf(acc[i][j][r]);
            }
}

// ---------- LayerNorm over 1152, one WAVE per row (r13) ----------
__global__ __launch_bounds__(64) void ln_row(unsigned short* __restrict__ qkvn,
                                             const float* __restrict__ gamma,
                                             const float* __restrict__ beta,
                                             unsigned short* __restrict__ vT) {
    const int row = blockIdx.x;  // b*2048 + l
    const int b = row >> 11, l = row & 2047;
    unsigned short* rp = qkvn + (size_t)row * 1152;
    const int lane = threadIdx.x;

    s16x8 v0 = *(const s16x8*)&rp[lane * 8];
    s16x8 v1 = *(const s16x8*)&rp[512 + lane * 8];
    unsigned int v2u = *(const unsigned int*)&rp[1024 + lane * 2];

    float f0[8], f1[8], f2[2];
    float s = 0.f, s2 = 0.f;
#pragma unroll
    for (int e = 0; e < 8; ++e) {
        f0[e] = bf2f((unsigned short)v0[e]);
        f1[e] = bf2f((unsigned short)v1[e]);
        s += f0[e] + f1[e];
        s2 += f0[e] * f0[e] + f1[e] * f1[e];
    }
    f2[0] = bf2f((unsigned short)(v2u & 0xFFFF));
    f2[1] = bf2f((unsigned short)(v2u >> 16));
    s += f2[0] + f2[1];
    s2 += f2[0] * f2[0] + f2[1] * f2[1];

#pragma unroll
    for (int off = 1; off < 64; off <<= 1) {
        s += __shfl_xor(s, off);
        s2 += __shfl_xor(s2, off);
    }
    const float mu = s * (1.0f / 1152.0f);
    float var = s2 * (1.0f / 1152.0f) - mu * mu;
    var = fmaxf(var, 0.0f);
    const float rstd = rsqrtf(var + 1e-5f);

    {
        s16x8 o;
#pragma unroll
        for (int e = 0; e < 8; ++e)
            o[e] = (short)f2bf((f0[e] - mu) * rstd * gamma[lane * 8 + e] + beta[lane * 8 + e]);
        *(s16x8*)&rp[lane * 8] = o;
        if (lane >= 8 && lane < 16) {  // v head (cols 64..127) -> transposed copy
            const int d0 = lane * 8 - 64;
#pragma unroll
            for (int e = 0; e < 8; ++e)
                vT[((size_t)(b * 64 + d0 + e)) * 2048 + l] = (unsigned short)o[e];
        }
    }
    {
        s16x8 o;
#pragma unroll
        for (int e = 0; e < 8; ++e)
            o[e] = (short)f2bf((f1[e] - mu) * rstd * gamma[512 + lane * 8 + e] + beta[512 + lane * 8 + e]);
        *(s16x8*)&rp[512 + lane * 8] = o;
    }
    {
        unsigned short o0 = f2bf((f2[0] - mu) * rstd * gamma[1024 + lane * 2] + beta[1024 + lane * 2]);
        unsigned short o1 = f2bf((f2[1] - mu) * rstd * gamma[1025 + lane * 2] + beta[1025 + lane * 2]);
        *(unsigned int*)&rp[1024 + lane * 2] = ((unsigned int)o1 << 16) | o0;
    }
}

// ---------- Flash-style causal multi-query attention (r16, unchanged) ----------
__global__ __launch_bounds__(512) void attn_kernel(const unsigned short* __restrict__ qkvn,
                                                   const unsigned short* __restrict__ vT,
                                                   unsigned short* __restrict__ obuf) {
    const int b = blockIdx.x >> 3, hp = blockIdx.x & 7;
    const int yy = blockIdx.y;
    const int qb = (yy < 16) ? (31 - yy) : (yy - 16);  // CU-paired: (31-a)+a = 33 iters/CU
    const int t = threadIdx.x;
    const int lane = t & 63, w = t >> 6;
    const int quad = lane >> 4, col = lane & 15;
    const int hl = w >> 2, wq = w & 3;   // head-local, wave-in-head

    __shared__ alignas(16) unsigned short Ks[2][4096];   // 16 KB swizzled, unpadded
    __shared__ alignas(16) unsigned short Vts[2][4096];  // 16 KB ([d][j] swizzled)
    __shared__ alignas(16) unsigned short PQ[8][16][72]; // Q-stage, then per-wave P^T [q][k]

    unsigned short(*Qs)[72] = (unsigned short(*)[72])PQ; // view as [128][72]

    const int srow = t >> 3;                  // 0..63
    const int schunk = t & 7;                 // global 8-short chunk
    const int ldsoff = srow * 64 + (schunk ^ (srow & 7)) * 8;  // swizzled LDS addr

    // stage Q for both heads, pre-scaled by 1/8 (exact in bf16)
#pragma unroll
    for (int hh = 0; hh < 2; ++hh) {
        const unsigned short* qsrc =
            qkvn + (size_t)(b * 2048 + qb * 64 + srow) * 1152 + 128 + (hp * 2 + hh) * 64 + schunk * 8;
        s16x8 v = *(const s16x8*)qsrc;
#pragma unroll
        for (int e = 0; e < 8; ++e)
            v[e] = (short)f2bf(bf2f((unsigned short)v[e]) * 0.125f);
        *(s16x8*)&Qs[hh * 64 + srow][schunk * 8] = v;
    }
    __syncthreads();
    const s16x8 qf0 = *(const s16x8*)&Qs[hl * 64 + wq * 16 + col][quad * 8];
    const s16x8 qf1 = *(const s16x8*)&Qs[hl * 64 + wq * 16 + col][32 + quad * 8];

    // stage K/V tile 0 (global reads linear; LDS writes swizzled)
    const unsigned short* kbase = qkvn + (size_t)(b * 2048 + srow) * 1152 + schunk * 8;  // + kb*64*1152
    const unsigned short* vbase = vT + (size_t)(b * 64 + srow) * 2048 + schunk * 8;      // + kb*64
    *(uint4*)&Ks[0][ldsoff]  = *(const uint4*)(kbase);
    *(uint4*)&Vts[0][ldsoff] = *(const uint4*)(vbase);
    __syncthreads();  // KV0 visible; all Q-frag reads done -> PQ reusable as P

    // fragment byte offsets into swizzled tiles (invariant; + nt*2048 per tile)
    const int fo0 = col * 128 + ((quad ^ (col & 7)) * 16);        // k-half 0
    const int fo1 = col * 128 + (((4 + quad) ^ (col & 7)) * 16);  // k-half 1

    s16x8 ones;
#pragma unroll
    for (int e = 0; e < 8; ++e) ones[e] = (short)0x3F80;  // bf16 1.0

    f32x4 Oacc[4];
    f32x4 lacc = {0.f, 0.f, 0.f, 0.f};
#pragma unroll
    for (int nt = 0; nt < 4; ++nt) Oacc[nt] = (f32x4){0.f, 0.f, 0.f, 0.f};

    const int qglob = qb * 64 + wq * 16 + col;    // this lane's q row (fixed)
    const int kloc0 = quad * 4;                   // + nt*16 + r = local k row

    for (int kb = 0; kb <= qb; ++kb) {
        const int p = kb & 1;
        uint4 kreg, vreg;
        if (kb < qb) {  // issue next tile's global loads before compute
            kreg = *(const uint4*)(kbase + (size_t)(kb + 1) * 64 * 1152);
            vreg = *(const uint4*)(vbase + (kb + 1) * 64);
        }
        const bool diag = (kb == qb);
        const char* kb8 = (const char*)Ks[p];
        const char* vb8 = (const char*)Vts[p];

        // S^T = K (Q/8)^T per k-tile nt -> mask -> exp -> packed P^T write [q][k]
#pragma unroll
        for (int nt = 0; nt < 4; ++nt) {
            s16x8 kf0 = *(const s16x8*)(kb8 + nt * 2048 + fo0);
            s16x8 kf1 = *(const s16x8*)(kb8 + nt * 2048 + fo1);
            f32x4 z = (f32x4){0.f, 0.f, 0.f, 0.f};
            z = MFMA16(kf0, qf0, z);   // A=K, B=Q  ->  S^T[k][q]
            z = MFMA16(kf1, qf1, z);
            ushort4 pk;
            unsigned short* pp = (unsigned short*)&pk;
#pragma unroll
            for (int r = 0; r < 4; ++r) {
                float sv = z[r];
                if (diag && (kb * 64 + nt * 16 + kloc0 + r > qglob)) sv = -1e30f;
                pp[r] = f2bf(__expf(sv - 12.0f));
            }
            *(ushort4*)&PQ[w][col][nt * 16 + kloc0] = pk;  // 8B packed write, k-contig
        }

        const s16x8 pf0 = *(const s16x8*)&PQ[w][col][quad * 8];        // B: P[q=col][k]
        const s16x8 pf1 = *(const s16x8*)&PQ[w][col][32 + quad * 8];
        lacc = MFMA16(ones, pf0, lacc);   // D[*][q] = l[q]
        lacc = MFMA16(ones, pf1, lacc);
#pragma unroll
        for (int nt = 0; nt < 4; ++nt) {
            s16x8 vf0 = *(const s16x8*)(vb8 + nt * 2048 + fo0);
            s16x8 vf1 = *(const s16x8*)(vb8 + nt * 2048 + fo1);
            Oacc[nt] = MFMA16(vf0, pf0, Oacc[nt]);   // A=V^T, B=P^T -> O^T[d][q]
            Oacc[nt] = MFMA16(vf1, pf1, Oacc[nt]);
        }

        if (kb < qb) {  // LDS-write prefetched tile into the other (swizzled) buffer
            *(uint4*)&Ks[p ^ 1][ldsoff]  = kreg;
            *(uint4*)&Vts[p ^ 1][ldsoff] = vreg;
        }
        __syncthreads();  // ONE barrier per iter
    }

    // epilogue: lane holds O[q=col][d=nt*16+quad*4+r]; l = lacc[0] (rows identical)
    const int h = hp * 2 + hl;
    const float inv = 1.0f / lacc[0];
    const size_t base = (((size_t)b * 2048 + qglob) * 16 + h) * 64 + kloc0;
#pragma unroll
    for (int nt = 0; nt < 4; ++nt) {
        ushort4 ov;
        unsigned short* op = (unsigned short*)&ov;
#pragma unroll
        for (int r = 0; r < 4; ++r) op[r] = f2bf(Oacc[nt][r] * inv);
        *(ushort4*)&obuf[base + nt * 16] = ov;  // 8B packed store, d-contig
    }
}

// ---------- launch ----------
extern "C" void kernel_launch(void* const* d_in, const int* in_sizes, int n_in,
                              void* d_out, int out_size, void* d_ws, size_t ws_size,
                              hipStream_t stream) {
    (void)in_sizes; (void)n_in; (void)out_size; (void)ws_size;
    const float* x     = (const float*)d_in[0];  // (2,2048,1024) fp32
    const float* Wqkv  = (const float*)d_in[1];  // (1152,1024)  fp32
    const float* gamma = (const float*)d_in[2];  // (1152,)      fp32
    const float* beta  = (const float*)d_in[3];  // (1152,)      fp32
    const float* Wfc   = (const float*)d_in[4];  // (1024,1024)  fp32
    float* out = (float*)d_out;                  // (2,2048,1024) fp32

    // ws >= 22,806,528 B (proven in round 5)
    char* ws = (char*)d_ws;
    unsigned short* xb   = (unsigned short*)ws;               // 8,388,608
    unsigned short* Wqb  = (unsigned short*)(ws + 8388608);   // 2,359,296
    unsigned short* Wfb  = (unsigned short*)(ws + 10747904);  // 2,097,152
    unsigned short* qkvn = (unsigned short*)(ws + 12845056);  // 9,437,184
    unsigned short* vT   = (unsigned short*)(ws + 22282240);  //   524,288
    unsigned short* abuf = (unsigned short*)ws;               // alias xb (dead after gemm1)

    cvt_all<<<dim3(3136), 256, 0, stream>>>(x, Wqkv, Wfc, xb, Wqb, Wfb);
    gemm_mn<false><<<dim3(32, 18), 256, 0, stream>>>(xb, Wqb, qkvn, 1024, 1152);
    ln_row<<<dim3(4096), 64, 0, stream>>>(qkvn, gamma, beta, vT);
    attn_kernel<<<dim3(16, 32), 512, 0, stream>>>(qkvn, vT, abuf);
    gemm_mn<true><<<dim3(32, 16), 256, 0, stream>>>(abuf, Wfb, out, 1024, 1024);
}

// Round 18
// 150.597 us; speedup vs baseline: 1.1511x; 1.0109x over previous
//
#include <hip/hip_runtime.h>
#include <stdint.h>

typedef __attribute__((ext_vector_type(8))) short s16x8;
typedef __attribute__((ext_vector_type(4))) float f32x4;

#define MFMA16(a, b, c) __builtin_amdgcn_mfma_f32_16x16x32_bf16((a), (b), (c), 0, 0, 0)

// ---------- helpers ----------
__device__ __forceinline__ unsigned short f2bf(float f) {
    unsigned int u = __float_as_uint(f);
    return (unsigned short)((u + 0x7FFFu + ((u >> 16) & 1u)) >> 16);
}
__device__ __forceinline__ float bf2f(unsigned short h) {
    return __uint_as_float(((unsigned int)h) << 16);
}
__device__ __forceinline__ void cvt8(unsigned short* dst, const float* src) {
    const float4 f0 = *(const float4*)(src);
    const float4 f1 = *(const float4*)(src + 4);
    s16x8 v;
    v[0] = (short)f2bf(f0.x); v[1] = (short)f2bf(f0.y);
    v[2] = (short)f2bf(f0.z); v[3] = (short)f2bf(f0.w);
    v[4] = (short)f2bf(f1.x); v[5] = (short)f2bf(f1.y);
    v[6] = (short)f2bf(f1.z); v[7] = (short)f2bf(f1.w);
    *(s16x8*)dst = v;
}
// async global->LDS DMA, 16 B/lane; LDS base wave-uniform, lane i -> base+i*16.
__device__ __forceinline__ void gl_lds16(const unsigned short* g, unsigned short* l) {
    __builtin_amdgcn_global_load_lds(
        (const __attribute__((address_space(1))) unsigned int*)g,
        (__attribute__((address_space(3))) unsigned int*)l,
        16, 0, 0);
}

// ---------- merged fp32 -> bf16 convert for x / Wqkv / Wfc (one launch) ----------
__global__ __launch_bounds__(256) void cvt_all(const float* __restrict__ x,
                                               const float* __restrict__ wq,
                                               const float* __restrict__ wf,
                                               unsigned short* __restrict__ xb,
                                               unsigned short* __restrict__ wqb,
                                               unsigned short* __restrict__ wfb) {
    const int blk = blockIdx.x;  // 0..3135
    const float* src;
    unsigned short* dst;
    int base;
    if (blk < 2048)      { src = x;  dst = xb;  base = blk; }
    else if (blk < 2624) { src = wq; dst = wqb; base = blk - 2048; }
    else                 { src = wf; dst = wfb; base = blk - 2624; }
    const int i = (base * 256 + threadIdx.x) * 8;
    cvt8(&dst[i], &src[i]);
}

// ---------- GEMM 128(M)x64(N): 512 thr / 8 waves, swizzled dbuf DMA ----------
// r17 ran 4 waves/block -> only 2.25 waves/SIMD on gemm1; per-iter barrier+DMA
// drain unhidden (m102 small-shape regime, pair ~83us). This round: 8 waves of
// 32x32 (2x2 mfma) on the SAME tile -> 18 waves/CU, 2x latency-hiding. LDS
// reads/iter rise 48->64 b128 but are conflict-free (r17 swizzle).
// Staging: each wave DMAs 2 A-chunks + 1 B-chunk (8 rows each) per iter.
template <bool OUT_F32>
__global__ __launch_bounds__(512) void gemm_mn(const unsigned short* __restrict__ A,
                                               const unsigned short* __restrict__ Bw,
                                               void* __restrict__ Cout, int K, int N) {
    const int bm = blockIdx.x, bn = blockIdx.y;
    const int t = threadIdx.x;
    const int lane = t & 63, w = t >> 6;          // 8 waves
    const int quad = lane >> 4, col = lane & 15;
    const int wm = (w >> 1) * 32, wn = (w & 1) * 32;  // wave = 32x32

    __shared__ alignas(16) unsigned short As[2][128 * 64];  // 2 x 16 KB, swizzled
    __shared__ alignas(16) unsigned short Bs[2][64 * 64];   // 2 x  8 KB, swizzled

    f32x4 acc[2][2];
#pragma unroll
    for (int i = 0; i < 2; ++i)
#pragma unroll
        for (int j = 0; j < 2; ++j) acc[i][j] = (f32x4){0.f, 0.f, 0.f, 0.f};

    const int lrow = lane >> 3;                      // 0..7
    const int lcol = ((lane & 7) ^ lrow) * 8;        // swizzled global chunk
    // wave w stages A rows [w*16, w*16+16) (2 issues) and B rows [w*8, w*8+8)
    const unsigned short* Ap = A + (size_t)(bm * 128 + w * 16 + lrow) * K + lcol;
    const unsigned short* Bp = Bw + (size_t)(bn * 64 + w * 8 + lrow) * K + lcol;

    // prime tile 0 into buffer 0
#pragma unroll
    for (int j = 0; j < 2; ++j)
        gl_lds16(Ap + (size_t)(j * 8) * K, &As[0][(w * 16 + j * 8) * 64]);
    gl_lds16(Bp, &Bs[0][(w * 8) * 64]);
    __syncthreads();  // drain: tile 0 visible

    // swizzled fragment chunk offsets (shorts): row*64 + ((s*4+quad)^(col&7))*8
    const int c7 = col & 7;
    const int fs0 = ((0 * 4 + quad) ^ c7) * 8;
    const int fs1 = ((1 * 4 + quad) ^ c7) * 8;

    for (int k0 = 0; k0 < K; k0 += 64) {
        const int p = (k0 >> 6) & 1;
        if (k0 + 64 < K) {  // stream next tile into the other buffer (no drain)
#pragma unroll
            for (int j = 0; j < 2; ++j)
                gl_lds16(Ap + (size_t)(j * 8) * K + k0 + 64, &As[p ^ 1][(w * 16 + j * 8) * 64]);
            gl_lds16(Bp + k0 + 64, &Bs[p ^ 1][(w * 8) * 64]);
        }
#pragma unroll
        for (int s = 0; s < 2; ++s) {
            const int fs = s ? fs1 : fs0;
            s16x8 af[2], bfr[2];
#pragma unroll
            for (int i = 0; i < 2; ++i)
                af[i] = *(const s16x8*)&As[p][(wm + i * 16 + col) * 64 + fs];
#pragma unroll
            for (int j = 0; j < 2; ++j)
                bfr[j] = *(const s16x8*)&Bs[p][(wn + j * 16 + col) * 64 + fs];
#pragma unroll
            for (int i = 0; i < 2; ++i)
#pragma unroll
                for (int j = 0; j < 2; ++j)
                    acc[i][j] = MFMA16(af[i], bfr[j], acc[i][j]);
        }
        __syncthreads();
    }
    const int rowb = bm * 128 + wm + quad * 4;
    const int colb = bn * 64 + wn + col;
#pragma unroll
    for (int i = 0; i < 2; ++i)
#pragma unroll
        for (int j = 0; j < 2; ++j)
#pragma unroll
            for (int r = 0; r < 4; ++r) {
                size_t off = (size_t)(rowb + i * 16 + r) * N + colb + j * 16;
                if (OUT_F32) ((float*)Cout)[off] = acc[i][j][r];
                else ((unsigned short*)Cout)[off] = f2bf(acc[i][j][r]);
            }
}

// ---------- LayerNorm over 1152, one WAVE per row (r13) ----------
__global__ __launch_bounds__(64) void ln_row(unsigned short* __restrict__ qkvn,
                                             const float* __restrict__ gamma,
                                             const float* __restrict__ beta,
                                             unsigned short* __restrict__ vT) {
    const int row = blockIdx.x;  // b*2048 + l
    const int b = row >> 11, l = row & 2047;
    unsigned short* rp = qkvn + (size_t)row * 1152;
    const int lane = threadIdx.x;

    s16x8 v0 = *(const s16x8*)&rp[lane * 8];
    s16x8 v1 = *(const s16x8*)&rp[512 + lane * 8];
    unsigned int v2u = *(const unsigned int*)&rp[1024 + lane * 2];

    float f0[8], f1[8], f2[2];
    float s = 0.f, s2 = 0.f;
#pragma unroll
    for (int e = 0; e < 8; ++e) {
        f0[e] = bf2f((unsigned short)v0[e]);
        f1[e] = bf2f((unsigned short)v1[e]);
        s += f0[e] + f1[e];
        s2 += f0[e] * f0[e] + f1[e] * f1[e];
    }
    f2[0] = bf2f((unsigned short)(v2u & 0xFFFF));
    f2[1] = bf2f((unsigned short)(v2u >> 16));
    s += f2[0] + f2[1];
    s2 += f2[0] * f2[0] + f2[1] * f2[1];

#pragma unroll
    for (int off = 1; off < 64; off <<= 1) {
        s += __shfl_xor(s, off);
        s2 += __shfl_xor(s2, off);
    }
    const float mu = s * (1.0f / 1152.0f);
    float var = s2 * (1.0f / 1152.0f) - mu * mu;
    var = fmaxf(var, 0.0f);
    const float rstd = rsqrtf(var + 1e-5f);

    {
        s16x8 o;
#pragma unroll
        for (int e = 0; e < 8; ++e)
            o[e] = (short)f2bf((f0[e] - mu) * rstd * gamma[lane * 8 + e] + beta[lane * 8 + e]);
        *(s16x8*)&rp[lane * 8] = o;
        if (lane >= 8 && lane < 16) {  // v head (cols 64..127) -> transposed copy
            const int d0 = lane * 8 - 64;
#pragma unroll
            for (int e = 0; e < 8; ++e)
                vT[((size_t)(b * 64 + d0 + e)) * 2048 + l] = (unsigned short)o[e];
        }
    }
    {
        s16x8 o;
#pragma unroll
        for (int e = 0; e < 8; ++e)
            o[e] = (short)f2bf((f1[e] - mu) * rstd * gamma[512 + lane * 8 + e] + beta[512 + lane * 8 + e]);
        *(s16x8*)&rp[512 + lane * 8] = o;
    }
    {
        unsigned short o0 = f2bf((f2[0] - mu) * rstd * gamma[1024 + lane * 2] + beta[1024 + lane * 2]);
        unsigned short o1 = f2bf((f2[1] - mu) * rstd * gamma[1025 + lane * 2] + beta[1025 + lane * 2]);
        *(unsigned int*)&rp[1024 + lane * 2] = ((unsigned int)o1 << 16) | o0;
    }
}

// ---------- Flash-style causal multi-query attention (r16, unchanged) ----------
__global__ __launch_bounds__(512) void attn_kernel(const unsigned short* __restrict__ qkvn,
                                                   const unsigned short* __restrict__ vT,
                                                   unsigned short* __restrict__ obuf) {
    const int b = blockIdx.x >> 3, hp = blockIdx.x & 7;
    const int yy = blockIdx.y;
    const int qb = (yy < 16) ? (31 - yy) : (yy - 16);  // CU-paired: (31-a)+a = 33 iters/CU
    const int t = threadIdx.x;
    const int lane = t & 63, w = t >> 6;
    const int quad = lane >> 4, col = lane & 15;
    const int hl = w >> 2, wq = w & 3;   // head-local, wave-in-head

    __shared__ alignas(16) unsigned short Ks[2][4096];   // 16 KB swizzled, unpadded
    __shared__ alignas(16) unsigned short Vts[2][4096];  // 16 KB ([d][j] swizzled)
    __shared__ alignas(16) unsigned short PQ[8][16][72]; // Q-stage, then per-wave P^T [q][k]

    unsigned short(*Qs)[72] = (unsigned short(*)[72])PQ; // view as [128][72]

    const int srow = t >> 3;                  // 0..63
    const int schunk = t & 7;                 // global 8-short chunk
    const int ldsoff = srow * 64 + (schunk ^ (srow & 7)) * 8;  // swizzled LDS addr

    // stage Q for both heads, pre-scaled by 1/8 (exact in bf16)
#pragma unroll
    for (int hh = 0; hh < 2; ++hh) {
        const unsigned short* qsrc =
            qkvn + (size_t)(b * 2048 + qb * 64 + srow) * 1152 + 128 + (hp * 2 + hh) * 64 + schunk * 8;
        s16x8 v = *(const s16x8*)qsrc;
#pragma unroll
        for (int e = 0; e < 8; ++e)
            v[e] = (short)f2bf(bf2f((unsigned short)v[e]) * 0.125f);
        *(s16x8*)&Qs[hh * 64 + srow][schunk * 8] = v;
    }
    __syncthreads();
    const s16x8 qf0 = *(const s16x8*)&Qs[hl * 64 + wq * 16 + col][quad * 8];
    const s16x8 qf1 = *(const s16x8*)&Qs[hl * 64 + wq * 16 + col][32 + quad * 8];

    // stage K/V tile 0 (global reads linear; LDS writes swizzled)
    const unsigned short* kbase = qkvn + (size_t)(b * 2048 + srow) * 1152 + schunk * 8;  // + kb*64*1152
    const unsigned short* vbase = vT + (size_t)(b * 64 + srow) * 2048 + schunk * 8;      // + kb*64
    *(uint4*)&Ks[0][ldsoff]  = *(const uint4*)(kbase);
    *(uint4*)&Vts[0][ldsoff] = *(const uint4*)(vbase);
    __syncthreads();  // KV0 visible; all Q-frag reads done -> PQ reusable as P

    // fragment byte offsets into swizzled tiles (invariant; + nt*2048 per tile)
    const int fo0 = col * 128 + ((quad ^ (col & 7)) * 16);        // k-half 0
    const int fo1 = col * 128 + (((4 + quad) ^ (col & 7)) * 16);  // k-half 1

    s16x8 ones;
#pragma unroll
    for (int e = 0; e < 8; ++e) ones[e] = (short)0x3F80;  // bf16 1.0

    f32x4 Oacc[4];
    f32x4 lacc = {0.f, 0.f, 0.f, 0.f};
#pragma unroll
    for (int nt = 0; nt < 4; ++nt) Oacc[nt] = (f32x4){0.f, 0.f, 0.f, 0.f};

    const int qglob = qb * 64 + wq * 16 + col;    // this lane's q row (fixed)
    const int kloc0 = quad * 4;                   // + nt*16 + r = local k row

    for (int kb = 0; kb <= qb; ++kb) {
        const int p = kb & 1;
        uint4 kreg, vreg;
        if (kb < qb) {  // issue next tile's global loads before compute
            kreg = *(const uint4*)(kbase + (size_t)(kb + 1) * 64 * 1152);
            vreg = *(const uint4*)(vbase + (kb + 1) * 64);
        }
        const bool diag = (kb == qb);
        const char* kb8 = (const char*)Ks[p];
        const char* vb8 = (const char*)Vts[p];

        // S^T = K (Q/8)^T per k-tile nt -> mask -> exp -> packed P^T write [q][k]
#pragma unroll
        for (int nt = 0; nt < 4; ++nt) {
            s16x8 kf0 = *(const s16x8*)(kb8 + nt * 2048 + fo0);
            s16x8 kf1 = *(const s16x8*)(kb8 + nt * 2048 + fo1);
            f32x4 z = (f32x4){0.f, 0.f, 0.f, 0.f};
            z = MFMA16(kf0, qf0, z);   // A=K, B=Q  ->  S^T[k][q]
            z = MFMA16(kf1, qf1, z);
            ushort4 pk;
            unsigned short* pp = (unsigned short*)&pk;
#pragma unroll
            for (int r = 0; r < 4; ++r) {
                float sv = z[r];
                if (diag && (kb * 64 + nt * 16 + kloc0 + r > qglob)) sv = -1e30f;
                pp[r] = f2bf(__expf(sv - 12.0f));
            }
            *(ushort4*)&PQ[w][col][nt * 16 + kloc0] = pk;  // 8B packed write, k-contig
        }

        const s16x8 pf0 = *(const s16x8*)&PQ[w][col][quad * 8];        // B: P[q=col][k]
        const s16x8 pf1 = *(const s16x8*)&PQ[w][col][32 + quad * 8];
        lacc = MFMA16(ones, pf0, lacc);   // D[*][q] = l[q]
        lacc = MFMA16(ones, pf1, lacc);
#pragma unroll
        for (int nt = 0; nt < 4; ++nt) {
            s16x8 vf0 = *(const s16x8*)(vb8 + nt * 2048 + fo0);
            s16x8 vf1 = *(const s16x8*)(vb8 + nt * 2048 + fo1);
            Oacc[nt] = MFMA16(vf0, pf0, Oacc[nt]);   // A=V^T, B=P^T -> O^T[d][q]
            Oacc[nt] = MFMA16(vf1, pf1, Oacc[nt]);
        }

        if (kb < qb) {  // LDS-write prefetched tile into the other (swizzled) buffer
            *(uint4*)&Ks[p ^ 1][ldsoff]  = kreg;
            *(uint4*)&Vts[p ^ 1][ldsoff] = vreg;
        }
        __syncthreads();  // ONE barrier per iter
    }

    // epilogue: lane holds O[q=col][d=nt*16+quad*4+r]; l = lacc[0] (rows identical)
    const int h = hp * 2 + hl;
    const float inv = 1.0f / lacc[0];
    const size_t base = (((size_t)b * 2048 + qglob) * 16 + h) * 64 + kloc0;
#pragma unroll
    for (int nt = 0; nt < 4; ++nt) {
        ushort4 ov;
        unsigned short* op = (unsigned short*)&ov;
#pragma unroll
        for (int r = 0; r < 4; ++r) op[r] = f2bf(Oacc[nt][r] * inv);
        *(ushort4*)&obuf[base + nt * 16] = ov;  // 8B packed store, d-contig
    }
}

// ---------- launch ----------
extern "C" void kernel_launch(void* const* d_in, const int* in_sizes, int n_in,
                              void* d_out, int out_size, void* d_ws, size_t ws_size,
                              hipStream_t stream) {
    (void)in_sizes; (void)n_in; (void)out_size; (void)ws_size;
    const float* x     = (const float*)d_in[0];  // (2,2048,1024) fp32
    const float* Wqkv  = (const float*)d_in[1];  // (1152,1024)  fp32
    const float* gamma = (const float*)d_in[2];  // (1152,)      fp32
    const float* beta  = (const float*)d_in[3];  // (1152,)      fp32
    const float* Wfc   = (const float*)d_in[4];  // (1024,1024)  fp32
    float* out = (float*)d_out;                  // (2,2048,1024) fp32

    // ws >= 22,806,528 B (proven in round 5)
    char* ws = (char*)d_ws;
    unsigned short* xb   = (unsigned short*)ws;               // 8,388,608
    unsigned short* Wqb  = (unsigned short*)(ws + 8388608);   // 2,359,296
    unsigned short* Wfb  = (unsigned short*)(ws + 10747904);  // 2,097,152
    unsigned short* qkvn = (unsigned short*)(ws + 12845056);  // 9,437,184
    unsigned short* vT   = (unsigned short*)(ws + 22282240);  //   524,288
    unsigned short* abuf = (unsigned short*)ws;               // alias xb (dead after gemm1)

    cvt_all<<<dim3(3136), 256, 0, stream>>>(x, Wqkv, Wfc, xb, Wqb, Wfb);
    gemm_mn<false><<<dim3(32, 18), 512, 0, stream>>>(xb, Wqb, qkvn, 1024, 1152);
    ln_row<<<dim3(4096), 64, 0, stream>>>(qkvn, gamma, beta, vT);
    attn_kernel<<<dim3(16, 32), 512, 0, stream>>>(qkvn, vT, abuf);
    gemm_mn<true><<<dim3(32, 16), 512, 0, stream>>>(abuf, Wfb, out, 1024, 1024);
}